// Round 11
// baseline (2114.123 us; speedup 1.0000x reference)
//
#include <hip/hip_runtime.h>
#include <hip/hip_bf16.h>

// Problem constants
#define BB 64
#define TT 2048
#define II 128
#define HH 256
#define OO 128

typedef float f32x2 __attribute__((ext_vector_type(2)));
typedef float f32x4v __attribute__((ext_vector_type(4)));
typedef short bf16x8 __attribute__((ext_vector_type(8)));
typedef unsigned short ushortv4 __attribute__((ext_vector_type(4)));

__device__ __forceinline__ float bf16bits_to_f32(unsigned short u) {
    return __uint_as_float((unsigned)u << 16);
}
__device__ __forceinline__ unsigned short f2bf(float f) {
    union { __hip_bfloat16 h; unsigned short u; } cv;
    cv.h = __float2bfloat16(f);   // RNE
    return cv.u;
}

// ---------------------------------------------------------------------------
// Padé-rational tanh (Eigen/XLA float coefficients; verified by hand at
// x=1,3,5 to <=5e-5 abs err; valid |x|<~15, pre-activations are N(0,~1.2)
// so no clamp needed). Packed numerator/denominator; ONE v_rcp per 4 values
// via rcp(Q1*Q2*Q3*Q4) + cross-multiplication -> trans per wave: 16 -> 2.
// ---------------------------------------------------------------------------
#define PA1  4.89352455891786e-03f
#define PA3  6.37261928875436e-04f
#define PA5  1.48572235717979e-05f
#define PA7  5.12229709037114e-08f
#define PA9  -8.60467152213735e-11f
#define PA11 2.00018790482477e-13f
#define PA13 -2.76076847742355e-16f
#define QB0  4.89352518554385e-03f
#define QB2  2.26843463243900e-03f
#define QB4  1.18534705686654e-04f
#define QB6  1.19825839466702e-06f

__device__ __forceinline__ void pade_nd(f32x2 x, f32x2* n, f32x2* d) {
    f32x2 z = x * x;
    f32x2 p = {PA13, PA13};
    p = p * z + PA11;
    p = p * z + PA9;
    p = p * z + PA7;
    p = p * z + PA5;
    p = p * z + PA3;
    p = p * z + PA1;
    *n = p * x;
    f32x2 q = {QB6, QB6};
    q = q * z + QB4;
    q = q * z + QB2;
    q = q * z + QB0;
    *d = q;
}

// tanh of 4 values (two packed pairs) with a single v_rcp
#define TANH4(xA, xB, o0, o1, o2, o3) { \
    f32x2 nA, dA, nB, dB; \
    pade_nd(xA, &nA, &dA); pade_nd(xB, &nB, &dB); \
    float t1 = dA.x * dA.y, t2 = dB.x * dB.y; \
    float r = __builtin_amdgcn_rcpf(t1 * t2); \
    float rA = r * t2, rB = r * t1; \
    o0 = nA.x * dA.y * rA; o1 = nA.y * dA.x * rA; \
    o2 = nB.x * dB.y * rB; o3 = nB.y * dB.x * rB; }

// within-32 permutation: storage position p holds true column
//   T(p) = (p & ~31) + 16*(p&1) + ((p&31)>>1);  pos(c) = (c&~31)+2*(c&15)+((c&31)>>4)

// ---------------------------------------------------------------------------
// Phase 1 GEMM: writes TRANSPOSED, permuted xprojT[blk][t][pos][m16] with
// combined bias (bi+bh), so the recurrence C-init is 2 dwordx4, zero movs.
// ---------------------------------------------------------------------------
#define BM 64
#define BN 64
#define BKT 32

__global__ __launch_bounds__(256) void gemm_f32_bt(
    const float* __restrict__ A, const float* __restrict__ B,
    const float* __restrict__ bias, const float* __restrict__ bias2,
    float* __restrict__ CT, int M, int N, int K)
{
    __shared__ __align__(16) float As[BKT][BM + 4];
    __shared__ __align__(16) float Bs[BKT][BN + 4];

    const int t  = threadIdx.x;
    const int m0 = blockIdx.x * BM;
    const int n0 = blockIdx.y * BN;
    const int r  = t >> 3;         // 0..31
    const int kq = (t & 7) * 4;    // 0,4,...,28
    const int tx = t & 15;
    const int ty = t >> 4;

    float acc[4][4] = {};

    for (int k0 = 0; k0 < K; k0 += BKT) {
        float4 a0 = *(const float4*)&A[(size_t)(m0 + r)      * K + k0 + kq];
        float4 a1 = *(const float4*)&A[(size_t)(m0 + r + 32) * K + k0 + kq];
        float4 b0 = *(const float4*)&B[(size_t)(n0 + r)      * K + k0 + kq];
        float4 b1 = *(const float4*)&B[(size_t)(n0 + r + 32) * K + k0 + kq];

        __syncthreads();
        As[kq + 0][r] = a0.x; As[kq + 1][r] = a0.y; As[kq + 2][r] = a0.z; As[kq + 3][r] = a0.w;
        As[kq + 0][r + 32] = a1.x; As[kq + 1][r + 32] = a1.y; As[kq + 2][r + 32] = a1.z; As[kq + 3][r + 32] = a1.w;
        Bs[kq + 0][r] = b0.x; Bs[kq + 1][r] = b0.y; Bs[kq + 2][r] = b0.z; Bs[kq + 3][r] = b0.w;
        Bs[kq + 0][r + 32] = b1.x; Bs[kq + 1][r + 32] = b1.y; Bs[kq + 2][r + 32] = b1.z; Bs[kq + 3][r + 32] = b1.w;
        __syncthreads();

#pragma unroll
        for (int k = 0; k < BKT; ++k) {
            float4 avv = *(const float4*)&As[k][ty * 4];
            float4 bvv = *(const float4*)&Bs[k][tx * 4];
            const float* av = &avv.x;
            const float* bv = &bvv.x;
#pragma unroll
            for (int i = 0; i < 4; ++i)
#pragma unroll
                for (int j = 0; j < 4; ++j)
                    acc[i][j] = fmaf(av[i], bv[j], acc[i][j]);
        }
    }

#pragma unroll
    for (int i = 0; i < 4; ++i) {
        const int mg = m0 + ty * 4 + i;      // global row = b*TT + t
        const int bb = mg >> 11;             // batch (TT = 2048)
        const int tt = mg & 2047;            // timestep
#pragma unroll
        for (int j = 0; j < 4; ++j) {
            const int c = n0 + tx * 4 + j;   // true column
            float v = acc[i][j] + bias[c] + bias2[c];
            const int pos = (c & ~31) + 2 * (c & 15) + ((c & 31) >> 4);
            CT[(((size_t)(bb >> 4) * TT + tt) * HH + pos) * 16 + (bb & 15)] = v;
        }
    }
}

// ---------------------------------------------------------------------------
// Phase 3 GEMM (unchanged R8): hs bf16 within-32 permuted; As staging
// un-permutes (rows {kh, kh+16, kh+1, kh+17}).
// ---------------------------------------------------------------------------
__global__ __launch_bounds__(256) void gemm_bf16a_bt(
    const unsigned short* __restrict__ A, const float* __restrict__ B,
    const float* __restrict__ bias, float* __restrict__ C,
    int M, int N, int K)
{
    __shared__ __align__(16) float As[BKT][BM + 4];
    __shared__ __align__(16) float Bs[BKT][BN + 4];

    const int t  = threadIdx.x;
    const int m0 = blockIdx.x * BM;
    const int n0 = blockIdx.y * BN;
    const int r  = t >> 3;
    const int kq = (t & 7) * 4;
    const int kh = kq >> 1;        // un-permute
    const int tx = t & 15;
    const int ty = t >> 4;

    float acc[4][4] = {};

    for (int k0 = 0; k0 < K; k0 += BKT) {
        ushortv4 a0 = *(const ushortv4*)&A[(size_t)(m0 + r)      * K + k0 + kq];
        ushortv4 a1 = *(const ushortv4*)&A[(size_t)(m0 + r + 32) * K + k0 + kq];
        float4  b0 = *(const float4*)&B[(size_t)(n0 + r)      * K + k0 + kq];
        float4  b1 = *(const float4*)&B[(size_t)(n0 + r + 32) * K + k0 + kq];

        __syncthreads();
        As[kh + 0][r]  = bf16bits_to_f32(a0[0]); As[kh + 16][r] = bf16bits_to_f32(a0[1]);
        As[kh + 1][r]  = bf16bits_to_f32(a0[2]); As[kh + 17][r] = bf16bits_to_f32(a0[3]);
        As[kh + 0][r + 32]  = bf16bits_to_f32(a1[0]); As[kh + 16][r + 32] = bf16bits_to_f32(a1[1]);
        As[kh + 1][r + 32]  = bf16bits_to_f32(a1[2]); As[kh + 17][r + 32] = bf16bits_to_f32(a1[3]);
        Bs[kq + 0][r] = b0.x; Bs[kq + 1][r] = b0.y; Bs[kq + 2][r] = b0.z; Bs[kq + 3][r] = b0.w;
        Bs[kq + 0][r + 32] = b1.x; Bs[kq + 1][r + 32] = b1.y; Bs[kq + 2][r + 32] = b1.z; Bs[kq + 3][r + 32] = b1.w;
        __syncthreads();

#pragma unroll
        for (int k = 0; k < BKT; ++k) {
            float4 avv = *(const float4*)&As[k][ty * 4];
            float4 bvv = *(const float4*)&Bs[k][tx * 4];
            const float* av = &avv.x;
            const float* bv = &bvv.x;
#pragma unroll
            for (int i = 0; i < 4; ++i)
#pragma unroll
                for (int j = 0; j < 4; ++j)
                    acc[i][j] = fmaf(av[i], bv[j], acc[i][j]);
        }
    }

#pragma unroll
    for (int i = 0; i < 4; ++i) {
        float4 o;
        o.x = acc[i][0] + bias[n0 + tx * 4 + 0];
        o.y = acc[i][1] + bias[n0 + tx * 4 + 1];
        o.z = acc[i][2] + bias[n0 + tx * 4 + 2];
        o.w = acc[i][3] + bias[n0 + tx * 4 + 3];
        *(float4*)&C[(size_t)(m0 + ty * 4 + i) * N + n0 + tx * 4] = o;
    }
}

// ---------------------------------------------------------------------------
// Recurrence v11 = R8 structure (__syncthreads; deferred stores; prefetch)
//  + Padé tanh with shared rcp (trans/wave 16 -> 2; the 512 cyc/SIMD-step
//    trans-unit cost identified from R10's VALUBusy fit)
//  + xprojT: C-init = 2 dwordx4 direct loads (no movs, 1 pointer)
//  + unroll-2 ping-pong registers (compile-time LDS parity)
// ---------------------------------------------------------------------------
#define G 16
#define HPAD 264    // ushorts per h row (528B)

__global__ __launch_bounds__(512) __attribute__((amdgpu_waves_per_eu(2, 2)))
void rnn_recurrence_mfma(
    const float* __restrict__ xprojT, const float* __restrict__ Wh,
    unsigned short* __restrict__ hs)
{
    __shared__ __align__(16) unsigned short hbl[2][G][HPAD];

    const int blk  = blockIdx.x;         // 0..3
    const int tid  = threadIdx.x;        // 0..511
    const int wave = tid >> 6;           // 0..7
    const int lane = tid & 63;
    const int l15  = lane & 15;
    const int lg   = lane >> 4;          // 0..3
    const int n0   = wave * 32;          // wave's 32-unit block

    // ---- one-time B-frags (within-32 K-gather, v6/v8-verified)
#define LOADB(nt, kt, dst) { \
        const float* wp = Wh + (size_t)(n0 + (nt)*16 + l15) * HH + (kt)*32 + lg*4; \
        dst[0] = (short)f2bf(wp[0]);  dst[1] = (short)f2bf(wp[16]); \
        dst[2] = (short)f2bf(wp[1]);  dst[3] = (short)f2bf(wp[17]); \
        dst[4] = (short)f2bf(wp[2]);  dst[5] = (short)f2bf(wp[18]); \
        dst[6] = (short)f2bf(wp[3]);  dst[7] = (short)f2bf(wp[19]); }

    bf16x8 B00, B01, B02, B03, B04, B05, B06, B07;
    bf16x8 B10, B11, B12, B13, B14, B15, B16, B17;
    LOADB(0, 0, B00) LOADB(0, 1, B01) LOADB(0, 2, B02) LOADB(0, 3, B03)
    LOADB(0, 4, B04) LOADB(0, 5, B05) LOADB(0, 6, B06) LOADB(0, 7, B07)
    LOADB(1, 0, B10) LOADB(1, 1, B11) LOADB(1, 2, B12) LOADB(1, 3, B13)
    LOADB(1, 4, B14) LOADB(1, 5, B15) LOADB(1, 6, B16) LOADB(1, 7, B17)

    // xprojT base for this thread: [blk][t=0][pos = n0+2*l15][m = lg*4]
    const float* xT = xprojT + (((size_t)blk * TT + 0) * HH + (n0 + 2 * l15)) * 16 + lg * 4;

    // hs row pointers (4 batch rows), permuted col offset n0 + 2*l15;
    // base at position t = -1 (never stored; COND guards t=0)
    const int mb = blk * G + lg * 4;
    unsigned short* hq0 = hs + (size_t)(mb + 0) * TT * HH + n0 + 2 * l15 - HH;
    unsigned short* hq1 = hs + (size_t)(mb + 1) * TT * HH + n0 + 2 * l15 - HH;
    unsigned short* hq2 = hs + (size_t)(mb + 2) * TT * HH + n0 + 2 * l15 - HH;
    unsigned short* hq3 = hs + (size_t)(mb + 3) * TT * HH + n0 + 2 * l15 - HH;

    // prologue: zero h buffer 0; load x C-init for t=0
    for (int i = tid; i < G * HPAD / 2; i += 512)
        ((unsigned int*)hbl[0])[i] = 0u;
    f32x4v xA0 = *(const f32x4v*)xT;
    f32x4v xA1 = *(const f32x4v*)(xT + 16);
    f32x4v xB0, xB1;
    unsigned int svA0 = 0, svA1 = 0, svA2 = 0, svA3 = 0;
    unsigned int svB0 = 0, svB1 = 0, svB2 = 0, svB3 = 0;
    __syncthreads();

#define MM(a, b, c) c = __builtin_amdgcn_mfma_f32_16x16x32_bf16(a, b, c, 0, 0, 0);
    // one step, parity P compile-time. XC = C-init regs (loaded last step),
    // XN = next step's C-init (prefetched at top), SVST stored (step-1 data).
#define STEP(P, XC0, XC1, XN0, XN1, SVST, SVNEW, COND, SOFF) { \
    if (COND) { \
        *(unsigned int*)((char*)hq0 + (SOFF)) = SVST##0; \
        *(unsigned int*)((char*)hq1 + (SOFF)) = SVST##1; \
        *(unsigned int*)((char*)hq2 + (SOFF)) = SVST##2; \
        *(unsigned int*)((char*)hq3 + (SOFF)) = SVST##3; \
    } \
    xT += (size_t)HH * 16;                 /* advance one timestep */ \
    XN0 = *(const f32x4v*)xT; \
    XN1 = *(const f32x4v*)(xT + 16); \
    const unsigned short* hrow = &hbl[P][l15][lg * 8]; \
    bf16x8 a0 = *(const bf16x8*)(hrow + 0 * 32); \
    bf16x8 a1 = *(const bf16x8*)(hrow + 1 * 32); \
    bf16x8 a2 = *(const bf16x8*)(hrow + 2 * 32); \
    bf16x8 a3 = *(const bf16x8*)(hrow + 3 * 32); \
    bf16x8 a4 = *(const bf16x8*)(hrow + 4 * 32); \
    bf16x8 a5 = *(const bf16x8*)(hrow + 5 * 32); \
    bf16x8 a6 = *(const bf16x8*)(hrow + 6 * 32); \
    bf16x8 a7 = *(const bf16x8*)(hrow + 7 * 32); \
    f32x4v c0 = XC0; \
    f32x4v c1 = XC1; \
    MM(a0, B00, c0) MM(a0, B10, c1) \
    MM(a1, B01, c0) MM(a1, B11, c1) \
    MM(a2, B02, c0) MM(a2, B12, c1) \
    MM(a3, B03, c0) MM(a3, B13, c1) \
    MM(a4, B04, c0) MM(a4, B14, c1) \
    MM(a5, B05, c0) MM(a5, B15, c1) \
    MM(a6, B06, c0) MM(a6, B16, c1) \
    MM(a7, B07, c0) MM(a7, B17, c1) \
    f32x2 pA = {c0[0], c0[1]}, pB = {c0[2], c0[3]}; \
    f32x2 pC = {c1[0], c1[1]}, pD = {c1[2], c1[3]}; \
    float th0, th1, th2, th3, th4, th5, th6, th7; \
    TANH4(pA, pB, th0, th1, th2, th3) \
    TANH4(pC, pD, th4, th5, th6, th7) \
    asm("v_cvt_pk_bf16_f32 %0, %1, %2" : "=v"(SVNEW##0) : "v"(th0), "v"(th4)); \
    asm("v_cvt_pk_bf16_f32 %0, %1, %2" : "=v"(SVNEW##1) : "v"(th1), "v"(th5)); \
    asm("v_cvt_pk_bf16_f32 %0, %1, %2" : "=v"(SVNEW##2) : "v"(th2), "v"(th6)); \
    asm("v_cvt_pk_bf16_f32 %0, %1, %2" : "=v"(SVNEW##3) : "v"(th3), "v"(th7)); \
    *(unsigned int*)&hbl[(P) ^ 1][lg * 4 + 0][n0 + 2 * l15] = SVNEW##0; \
    *(unsigned int*)&hbl[(P) ^ 1][lg * 4 + 1][n0 + 2 * l15] = SVNEW##1; \
    *(unsigned int*)&hbl[(P) ^ 1][lg * 4 + 2][n0 + 2 * l15] = SVNEW##2; \
    *(unsigned int*)&hbl[(P) ^ 1][lg * 4 + 3][n0 + 2 * l15] = SVNEW##3; \
    __syncthreads(); \
}

    for (int t = 0; t < TT; t += 2) {
        // step t (even): reads hbl[0] -> writes hbl[1]; stores sv(t-1)
        STEP(0, xA0, xA1, xB0, xB1, svB, svA, (t != 0), 0)
        // step t+1 (odd): reads hbl[1] -> writes hbl[0]; stores sv(t)
        STEP(1, xB0, xB1, xA0, xA1, svA, svB, 1, HH * 2)
        hq0 += 2 * HH; hq1 += 2 * HH; hq2 += 2 * HH; hq3 += 2 * HH;
    }

    // final stores: svB holds t = TT-1; hq now points at position TT-1
    *(unsigned int*)hq0 = svB0;
    *(unsigned int*)hq1 = svB1;
    *(unsigned int*)hq2 = svB2;
    *(unsigned int*)hq3 = svB3;
}

// ---------------------------------------------------------------------------
extern "C" void kernel_launch(void* const* d_in, const int* in_sizes, int n_in,
                              void* d_out, int out_size, void* d_ws, size_t ws_size,
                              hipStream_t stream)
{
    const float* x  = (const float*)d_in[0];   // [B,T,I]
    const float* Wi = (const float*)d_in[1];   // [H,I]
    const float* bi = (const float*)d_in[2];   // [H]
    const float* Wh = (const float*)d_in[3];   // [H,H]
    const float* bh = (const float*)d_in[4];   // [H]
    const float* Wo = (const float*)d_in[5];   // [O,H]
    const float* bo = (const float*)d_in[6];   // [O]
    float* out = (float*)d_out;                // [B,T,O] fp32

    const int M = BB * TT;                     // 131072 flattened rows

    // workspace: xprojT fp32 [4][T][256][16] (134MB) | hs bf16 [M,H] (67MB)
    float* xprojT = (float*)d_ws;
    unsigned short* hs = (unsigned short*)((char*)d_ws + (size_t)M * HH * sizeof(float));

    // Phase 1: xprojT = transpose-permuted (x*Wi^T + bi + bh)
    gemm_f32_bt<<<dim3(M / BM, HH / BN), 256, 0, stream>>>(x, Wi, bi, bh, xprojT, M, HH, II);

    // Phase 2: recurrence (4 CUs, 8 waves each, MFMA, Padé tanh)
    rnn_recurrence_mfma<<<dim3(4), 512, 0, stream>>>(xprojT, Wh, hs);

    // Phase 3: out = hs*Wo^T + bo (As staging un-permutes)
    gemm_bf16a_bt<<<dim3(M / BM, OO / BN), 256, 0, stream>>>(
        hs, Wo, bo, out, M, OO, HH);
}

// Round 12
// 1662.748 us; speedup vs baseline: 1.2715x; 1.2715x over previous
//
#include <hip/hip_runtime.h>
#include <hip/hip_bf16.h>

// Problem constants
#define BB 64
#define TT 2048
#define II 128
#define HH 256
#define OO 128

typedef float f32x2 __attribute__((ext_vector_type(2)));
typedef float f32x4v __attribute__((ext_vector_type(4)));
typedef short bf16x8 __attribute__((ext_vector_type(8)));
typedef unsigned short ushortv4 __attribute__((ext_vector_type(4)));

__device__ __forceinline__ float bf16bits_to_f32(unsigned short u) {
    return __uint_as_float((unsigned)u << 16);
}
__device__ __forceinline__ unsigned short f2bf(float f) {
    union { __hip_bfloat16 h; unsigned short u; } cv;
    cv.h = __float2bfloat16(f);   // RNE
    return cv.u;
}

// ---------------------------------------------------------------------------
// Padé-rational tanh (Eigen/XLA float coefficients; |err|<=1e-4 for |x|<9,
// pre-activations are N(0,~1.2) so no clamp needed). ONE v_rcp per 4 values
// via rcp(d0*d1*d2*d3) + cross-multiplication -> trans per wave: 16 -> 2.
// ---------------------------------------------------------------------------
#define PA1  4.89352455891786e-03f
#define PA3  6.37261928875436e-04f
#define PA5  1.48572235717979e-05f
#define PA7  5.12229709037114e-08f
#define PA9  -8.60467152213735e-11f
#define PA11 2.00018790482477e-13f
#define PA13 -2.76076847742355e-16f
#define QB0  4.89352518554385e-03f
#define QB2  2.26843463243900e-03f
#define QB4  1.18534705686654e-04f
#define QB6  1.19825839466702e-06f

__device__ __forceinline__ void pade_nd(f32x2 x, f32x2* n, f32x2* d) {
    f32x2 z = x * x;
    f32x2 p = {PA13, PA13};
    p = p * z + PA11;
    p = p * z + PA9;
    p = p * z + PA7;
    p = p * z + PA5;
    p = p * z + PA3;
    p = p * z + PA1;
    *n = p * x;
    f32x2 q = {QB6, QB6};
    q = q * z + QB4;
    q = q * z + QB2;
    q = q * z + QB0;
    *d = q;
}

// tanh of 4 values (two packed pairs) with a single v_rcp
#define TANH4(xA, xB, o0, o1, o2, o3) { \
    f32x2 nA, dA, nB, dB; \
    pade_nd(xA, &nA, &dA); pade_nd(xB, &nB, &dB); \
    float t1 = dA.x * dA.y, t2 = dB.x * dB.y; \
    float r = __builtin_amdgcn_rcpf(t1 * t2); \
    float rA = r * t2, rB = r * t1; \
    o0 = nA.x * dA.y * rA; o1 = nA.y * dA.x * rA; \
    o2 = nB.x * dB.y * rB; o3 = nB.y * dB.x * rB; }

// within-32 permutation: storage position p holds true column
//   T(p) = (p & ~31) + 16*(p&1) + ((p&31)>>1)
// inverse: pos(c) = (c & ~31) + 2*(c&15) + ((c&31)>>4)

// ---------------------------------------------------------------------------
// Phase 1 GEMM (R8 verbatim): xproj[m][pos] = (x*Wi^T)[m][T(pos)] + bi + bh
// ---------------------------------------------------------------------------
#define BM 64
#define BN 64
#define BKT 32

__global__ __launch_bounds__(256) void gemm_f32_bt(
    const float* __restrict__ A, const float* __restrict__ B,
    const float* __restrict__ bias, const float* __restrict__ bias2,
    float* __restrict__ C, int M, int N, int K)
{
    __shared__ __align__(16) float As[BKT][BM + 4];
    __shared__ __align__(16) float Bs[BKT][BN + 4];

    const int t  = threadIdx.x;
    const int m0 = blockIdx.x * BM;
    const int n0 = blockIdx.y * BN;
    const int r  = t >> 3;         // 0..31
    const int kq = (t & 7) * 4;    // 0,4,...,28
    const int tx = t & 15;
    const int ty = t >> 4;

    float acc[4][4] = {};

    for (int k0 = 0; k0 < K; k0 += BKT) {
        float4 a0 = *(const float4*)&A[(size_t)(m0 + r)      * K + k0 + kq];
        float4 a1 = *(const float4*)&A[(size_t)(m0 + r + 32) * K + k0 + kq];
        float4 b0 = *(const float4*)&B[(size_t)(n0 + r)      * K + k0 + kq];
        float4 b1 = *(const float4*)&B[(size_t)(n0 + r + 32) * K + k0 + kq];

        __syncthreads();
        As[kq + 0][r] = a0.x; As[kq + 1][r] = a0.y; As[kq + 2][r] = a0.z; As[kq + 3][r] = a0.w;
        As[kq + 0][r + 32] = a1.x; As[kq + 1][r + 32] = a1.y; As[kq + 2][r + 32] = a1.z; As[kq + 3][r + 32] = a1.w;
        Bs[kq + 0][r] = b0.x; Bs[kq + 1][r] = b0.y; Bs[kq + 2][r] = b0.z; Bs[kq + 3][r] = b0.w;
        Bs[kq + 0][r + 32] = b1.x; Bs[kq + 1][r + 32] = b1.y; Bs[kq + 2][r + 32] = b1.z; Bs[kq + 3][r + 32] = b1.w;
        __syncthreads();

#pragma unroll
        for (int k = 0; k < BKT; ++k) {
            float4 avv = *(const float4*)&As[k][ty * 4];
            float4 bvv = *(const float4*)&Bs[k][tx * 4];
            const float* av = &avv.x;
            const float* bv = &bvv.x;
#pragma unroll
            for (int i = 0; i < 4; ++i)
#pragma unroll
                for (int j = 0; j < 4; ++j)
                    acc[i][j] = fmaf(av[i], bv[j], acc[i][j]);
        }
    }

#pragma unroll
    for (int i = 0; i < 4; ++i) {
#pragma unroll
        for (int j = 0; j < 4; ++j) {
            const int c = n0 + tx * 4 + j;     // true column
            float v = acc[i][j] + bias[c] + bias2[c];
            const int pos = (c & ~31) + 2 * (c & 15) + ((c & 31) >> 4);
            C[(size_t)(m0 + ty * 4 + i) * N + pos] = v;
        }
    }
}

// ---------------------------------------------------------------------------
// Phase 3 GEMM (R8 verbatim): hs bf16 within-32 permuted; As staging
// un-permutes (rows {kh, kh+16, kh+1, kh+17}).
// ---------------------------------------------------------------------------
__global__ __launch_bounds__(256) void gemm_bf16a_bt(
    const unsigned short* __restrict__ A, const float* __restrict__ B,
    const float* __restrict__ bias, float* __restrict__ C,
    int M, int N, int K)
{
    __shared__ __align__(16) float As[BKT][BM + 4];
    __shared__ __align__(16) float Bs[BKT][BN + 4];

    const int t  = threadIdx.x;
    const int m0 = blockIdx.x * BM;
    const int n0 = blockIdx.y * BN;
    const int r  = t >> 3;
    const int kq = (t & 7) * 4;
    const int kh = kq >> 1;        // un-permute
    const int tx = t & 15;
    const int ty = t >> 4;

    float acc[4][4] = {};

    for (int k0 = 0; k0 < K; k0 += BKT) {
        ushortv4 a0 = *(const ushortv4*)&A[(size_t)(m0 + r)      * K + k0 + kq];
        ushortv4 a1 = *(const ushortv4*)&A[(size_t)(m0 + r + 32) * K + k0 + kq];
        float4  b0 = *(const float4*)&B[(size_t)(n0 + r)      * K + k0 + kq];
        float4  b1 = *(const float4*)&B[(size_t)(n0 + r + 32) * K + k0 + kq];

        __syncthreads();
        As[kh + 0][r]  = bf16bits_to_f32(a0[0]); As[kh + 16][r] = bf16bits_to_f32(a0[1]);
        As[kh + 1][r]  = bf16bits_to_f32(a0[2]); As[kh + 17][r] = bf16bits_to_f32(a0[3]);
        As[kh + 0][r + 32]  = bf16bits_to_f32(a1[0]); As[kh + 16][r + 32] = bf16bits_to_f32(a1[1]);
        As[kh + 1][r + 32]  = bf16bits_to_f32(a1[2]); As[kh + 17][r + 32] = bf16bits_to_f32(a1[3]);
        Bs[kq + 0][r] = b0.x; Bs[kq + 1][r] = b0.y; Bs[kq + 2][r] = b0.z; Bs[kq + 3][r] = b0.w;
        Bs[kq + 0][r + 32] = b1.x; Bs[kq + 1][r + 32] = b1.y; Bs[kq + 2][r + 32] = b1.z; Bs[kq + 3][r + 32] = b1.w;
        __syncthreads();

#pragma unroll
        for (int k = 0; k < BKT; ++k) {
            float4 avv = *(const float4*)&As[k][ty * 4];
            float4 bvv = *(const float4*)&Bs[k][tx * 4];
            const float* av = &avv.x;
            const float* bv = &bvv.x;
#pragma unroll
            for (int i = 0; i < 4; ++i)
#pragma unroll
                for (int j = 0; j < 4; ++j)
                    acc[i][j] = fmaf(av[i], bv[j], acc[i][j]);
        }
    }

#pragma unroll
    for (int i = 0; i < 4; ++i) {
        float4 o;
        o.x = acc[i][0] + bias[n0 + tx * 4 + 0];
        o.y = acc[i][1] + bias[n0 + tx * 4 + 1];
        o.z = acc[i][2] + bias[n0 + tx * 4 + 2];
        o.w = acc[i][3] + bias[n0 + tx * 4 + 3];
        *(float4*)&C[(size_t)(m0 + ty * 4 + i) * N + n0 + tx * 4] = o;
    }
}

// ---------------------------------------------------------------------------
// Recurrence v12 = R8 VERBATIM except the tanh: Padé rational with shared
// rcp (trans ops per wave 16 -> 2, +~44 cheap VALU). Single-change A/B to
// pin the trans-unit cost. R11's regression was the confounded x-layout
// change (128B-stride loads), NOT the tanh — reverted here.
// ---------------------------------------------------------------------------
#define G 16
#define HPAD 264    // ushorts per h row (528B)

__global__ __launch_bounds__(512) __attribute__((amdgpu_waves_per_eu(2, 2)))
void rnn_recurrence_mfma(
    const float* __restrict__ xproj, const float* __restrict__ Wh,
    unsigned short* __restrict__ hs)
{
    __shared__ __align__(16) unsigned short hbl[2][G][HPAD];

    const int blk  = blockIdx.x;         // 0..3
    const int tid  = threadIdx.x;        // 0..511
    const int wave = tid >> 6;           // 0..7
    const int lane = tid & 63;
    const int l15  = lane & 15;
    const int lg   = lane >> 4;          // 0..3
    const int n0   = wave * 32;          // wave's 32-unit block

    // ---- one-time B-frags (within-32 K-gather, v6/v8-verified)
#define LOADB(nt, kt, dst) { \
        const float* wp = Wh + (size_t)(n0 + (nt)*16 + l15) * HH + (kt)*32 + lg*4; \
        dst[0] = (short)f2bf(wp[0]);  dst[1] = (short)f2bf(wp[16]); \
        dst[2] = (short)f2bf(wp[1]);  dst[3] = (short)f2bf(wp[17]); \
        dst[4] = (short)f2bf(wp[2]);  dst[5] = (short)f2bf(wp[18]); \
        dst[6] = (short)f2bf(wp[3]);  dst[7] = (short)f2bf(wp[19]); }

    bf16x8 B00, B01, B02, B03, B04, B05, B06, B07;
    bf16x8 B10, B11, B12, B13, B14, B15, B16, B17;
    LOADB(0, 0, B00) LOADB(0, 1, B01) LOADB(0, 2, B02) LOADB(0, 3, B03)
    LOADB(0, 4, B04) LOADB(0, 5, B05) LOADB(0, 6, B06) LOADB(0, 7, B07)
    LOADB(1, 0, B10) LOADB(1, 1, B11) LOADB(1, 2, B12) LOADB(1, 3, B13)
    LOADB(1, 4, B14) LOADB(1, 5, B15) LOADB(1, 6, B16) LOADB(1, 7, B17)

    // per-thread 4 batch rows (m = lg*4 + r), permuted col offset n0 + 2*l15
    const int mb = blk * G + lg * 4;
    const float* xq0 = xproj + (size_t)(mb + 0) * TT * HH + n0 + 2 * l15;
    const float* xq1 = xproj + (size_t)(mb + 1) * TT * HH + n0 + 2 * l15;
    const float* xq2 = xproj + (size_t)(mb + 2) * TT * HH + n0 + 2 * l15;
    const float* xq3 = xproj + (size_t)(mb + 3) * TT * HH + n0 + 2 * l15;
    unsigned short* hq0 = hs + (size_t)(mb + 0) * TT * HH + n0 + 2 * l15;
    unsigned short* hq1 = hs + (size_t)(mb + 1) * TT * HH + n0 + 2 * l15;
    unsigned short* hq2 = hs + (size_t)(mb + 2) * TT * HH + n0 + 2 * l15;
    unsigned short* hq3 = hs + (size_t)(mb + 3) * TT * HH + n0 + 2 * l15;

    // prologue: zero h buffer 0; load x for t=0
    for (int i = tid; i < G * HPAD / 2; i += 512)
        ((unsigned int*)hbl[0])[i] = 0u;
    float2 xv0 = *(const float2*)xq0;
    float2 xv1 = *(const float2*)xq1;
    float2 xv2 = *(const float2*)xq2;
    float2 xv3 = *(const float2*)xq3;
    __syncthreads();

    unsigned int sv0 = 0, sv1 = 0, sv2 = 0, sv3 = 0;

    for (int t = 0; t < TT; ++t) {
        const int p = t & 1;

        // A-fragments of current h (8 x ds_read_b128)
        const unsigned short* hrow = &hbl[p][l15][lg * 8];
        bf16x8 a0 = *(const bf16x8*)(hrow + 0 * 32);
        bf16x8 a1 = *(const bf16x8*)(hrow + 1 * 32);
        bf16x8 a2 = *(const bf16x8*)(hrow + 2 * 32);
        bf16x8 a3 = *(const bf16x8*)(hrow + 3 * 32);
        bf16x8 a4 = *(const bf16x8*)(hrow + 4 * 32);
        bf16x8 a5 = *(const bf16x8*)(hrow + 5 * 32);
        bf16x8 a6 = *(const bf16x8*)(hrow + 6 * 32);
        bf16x8 a7 = *(const bf16x8*)(hrow + 7 * 32);

        // deferred hs stores for t-1 (drain overlaps this whole step)
        if (t) {
            *(unsigned int*)hq0 = sv0; hq0 += HH;
            *(unsigned int*)hq1 = sv1; hq1 += HH;
            *(unsigned int*)hq2 = sv2; hq2 += HH;
            *(unsigned int*)hq3 = sv3; hq3 += HH;
        }

        // 16 MFMA: 2 chains of 8, C-in = x (bias pre-folded in phase 1)
        f32x4v c0 = {xv0.x, xv1.x, xv2.x, xv3.x};
        f32x4v c1 = {xv0.y, xv1.y, xv2.y, xv3.y};
        c0 = __builtin_amdgcn_mfma_f32_16x16x32_bf16(a0, B00, c0, 0, 0, 0);
        c1 = __builtin_amdgcn_mfma_f32_16x16x32_bf16(a0, B10, c1, 0, 0, 0);
        c0 = __builtin_amdgcn_mfma_f32_16x16x32_bf16(a1, B01, c0, 0, 0, 0);
        c1 = __builtin_amdgcn_mfma_f32_16x16x32_bf16(a1, B11, c1, 0, 0, 0);
        c0 = __builtin_amdgcn_mfma_f32_16x16x32_bf16(a2, B02, c0, 0, 0, 0);
        c1 = __builtin_amdgcn_mfma_f32_16x16x32_bf16(a2, B12, c1, 0, 0, 0);
        c0 = __builtin_amdgcn_mfma_f32_16x16x32_bf16(a3, B03, c0, 0, 0, 0);
        c1 = __builtin_amdgcn_mfma_f32_16x16x32_bf16(a3, B13, c1, 0, 0, 0);
        c0 = __builtin_amdgcn_mfma_f32_16x16x32_bf16(a4, B04, c0, 0, 0, 0);
        c1 = __builtin_amdgcn_mfma_f32_16x16x32_bf16(a4, B14, c1, 0, 0, 0);
        c0 = __builtin_amdgcn_mfma_f32_16x16x32_bf16(a5, B05, c0, 0, 0, 0);
        c1 = __builtin_amdgcn_mfma_f32_16x16x32_bf16(a5, B15, c1, 0, 0, 0);
        c0 = __builtin_amdgcn_mfma_f32_16x16x32_bf16(a6, B06, c0, 0, 0, 0);
        c1 = __builtin_amdgcn_mfma_f32_16x16x32_bf16(a6, B16, c1, 0, 0, 0);
        c0 = __builtin_amdgcn_mfma_f32_16x16x32_bf16(a7, B07, c0, 0, 0, 0);
        c1 = __builtin_amdgcn_mfma_f32_16x16x32_bf16(a7, B17, c1, 0, 0, 0);

        // epilogue: Padé tanh (2 trans/wave total), pack, b32 LDS write per row
        {
            f32x2 pA = {c0[0], c0[1]}, pB = {c0[2], c0[3]};
            f32x2 pC = {c1[0], c1[1]}, pD = {c1[2], c1[3]};
            float th0, th1, th2, th3, th4, th5, th6, th7;
            TANH4(pA, pB, th0, th1, th2, th3)
            TANH4(pC, pD, th4, th5, th6, th7)
            asm("v_cvt_pk_bf16_f32 %0, %1, %2" : "=v"(sv0) : "v"(th0), "v"(th4));
            asm("v_cvt_pk_bf16_f32 %0, %1, %2" : "=v"(sv1) : "v"(th1), "v"(th5));
            asm("v_cvt_pk_bf16_f32 %0, %1, %2" : "=v"(sv2) : "v"(th2), "v"(th6));
            asm("v_cvt_pk_bf16_f32 %0, %1, %2" : "=v"(sv3) : "v"(th3), "v"(th7));
            *(unsigned int*)&hbl[p ^ 1][lg * 4 + 0][n0 + 2 * l15] = sv0;
            *(unsigned int*)&hbl[p ^ 1][lg * 4 + 1][n0 + 2 * l15] = sv1;
            *(unsigned int*)&hbl[p ^ 1][lg * 4 + 2][n0 + 2 * l15] = sv2;
            *(unsigned int*)&hbl[p ^ 1][lg * 4 + 3][n0 + 2 * l15] = sv3;
        }

        // prefetch x for t+1 (pointer bump; last-step read is in-bounds junk)
        xq0 += HH; xq1 += HH; xq2 += HH; xq3 += HH;
        xv0 = *(const float2*)xq0;
        xv1 = *(const float2*)xq1;
        xv2 = *(const float2*)xq2;
        xv3 = *(const float2*)xq3;

        __syncthreads();
    }

    // final stores (t = TT-1)
    *(unsigned int*)hq0 = sv0;
    *(unsigned int*)hq1 = sv1;
    *(unsigned int*)hq2 = sv2;
    *(unsigned int*)hq3 = sv3;
}

// ---------------------------------------------------------------------------
extern "C" void kernel_launch(void* const* d_in, const int* in_sizes, int n_in,
                              void* d_out, int out_size, void* d_ws, size_t ws_size,
                              hipStream_t stream)
{
    const float* x  = (const float*)d_in[0];   // [B,T,I]
    const float* Wi = (const float*)d_in[1];   // [H,I]
    const float* bi = (const float*)d_in[2];   // [H]
    const float* Wh = (const float*)d_in[3];   // [H,H]
    const float* bh = (const float*)d_in[4];   // [H]
    const float* Wo = (const float*)d_in[5];   // [O,H]
    const float* bo = (const float*)d_in[6];   // [O]
    float* out = (float*)d_out;                // [B,T,O] fp32

    const int M = BB * TT;                     // 131072 flattened rows

    // workspace: xproj fp32 [M,H] (134MB, permuted) | hs bf16 [M,H] (67MB, permuted)
    float* xproj = (float*)d_ws;
    unsigned short* hs = (unsigned short*)((char*)d_ws + (size_t)M * HH * sizeof(float));

    // Phase 1: xproj = x*Wi^T + (bi+bh), within-32 permuted columns
    gemm_f32_bt<<<dim3(M / BM, HH / BN), 256, 0, stream>>>(x, Wi, bi, bh, xproj, M, HH, II);

    // Phase 2: recurrence (4 CUs, 8 waves each, MFMA, Padé tanh)
    rnn_recurrence_mfma<<<dim3(4), 512, 0, stream>>>(xproj, Wh, hs);

    // Phase 3: out = hs*Wo^T + bo (As staging un-permutes)
    gemm_bf16a_bt<<<dim3(M / BM, OO / BN), 256, 0, stream>>>(
        hs, Wo, bo, out, M, OO, HH);
}

// Round 13
// 1263.150 us; speedup vs baseline: 1.6737x; 1.3164x over previous
//
#include <hip/hip_runtime.h>
#include <hip/hip_bf16.h>

// Problem constants
#define BB 64
#define TT 2048
#define II 128
#define HH 256
#define OO 128

typedef float f32x4v __attribute__((ext_vector_type(4)));
typedef short bf16x8 __attribute__((ext_vector_type(8)));

__device__ __forceinline__ unsigned short f2bf(float f) {
    union { __hip_bfloat16 h; unsigned short u; } cv;
    cv.h = __float2bfloat16(f);   // RNE
    return cv.u;
}
__device__ __forceinline__ float tanh_fast(float x) {
    // tanh(x) = 1 - 2/(e^{2x}+1);  e^{2x} = 2^{x*2*log2(e)}
    float y = x * 2.88539008177793f;
    float e;
    asm("v_exp_f32 %0, %1" : "=v"(e) : "v"(y));
    return 1.0f - 2.0f * __builtin_amdgcn_rcpf(e + 1.0f);
}

// within-32 permutation: storage position p holds true column
//   T(p)   = (p & ~31) + 16*(p&1) + ((p&31)>>1)
//   pos(c) = (c & ~31) + 2*(c&15) + ((c&31)>>4)     (inverse; verified T(pos(c))=c)

#define MM(a, b, c) c = __builtin_amdgcn_mfma_f32_16x16x32_bf16(a, b, c, 0, 0, 0);

// ---------------------------------------------------------------------------
// Phase 1 (MFMA): xproj[m][pos] = (x*Wi^T)[m][T(pos)] + bi + bh
// Block 256 thr / 4 waves; M-tile 64; Wi staged to LDS as bf16 (natural);
// x converted fp32->bf16 in-register; bias folded into MFMA C-init.
// ---------------------------------------------------------------------------
#define WIPAD 136   // ushorts per wiL row (272B stride: same bank family as recurrence)

__global__ __launch_bounds__(256) void gemm1_mfma(
    const float* __restrict__ x, const float* __restrict__ Wi,
    const float* __restrict__ bi, const float* __restrict__ bh,
    float* __restrict__ xproj)
{
    __shared__ __align__(16) unsigned short wiL[HH][WIPAD];   // 256 x 136 (69.6 KB)

    const int tid = threadIdx.x;
    const int wv = tid >> 6, lane = tid & 63;
    const int l15 = lane & 15, lg = lane >> 4;
    const int m0 = blockIdx.x * 64 + wv * 16;

    // stage Wi -> LDS bf16 (coalesced flat reads)
    for (int e = tid; e < HH * II; e += 256)
        wiL[e >> 7][e & 127] = f2bf(Wi[e]);
    __syncthreads();

    // A-frags: x rows m0+l15, K=128 (4 subtiles of 32), fp32 -> bf16
    const float* xr = x + (size_t)(m0 + l15) * II + lg * 8;
    bf16x8 a0, a1, a2, a3;
#define LOADA1(q, dst) { \
        float4 u0 = *(const float4*)(xr + (q) * 32); \
        float4 u1 = *(const float4*)(xr + (q) * 32 + 4); \
        dst[0] = (short)f2bf(u0.x); dst[1] = (short)f2bf(u0.y); \
        dst[2] = (short)f2bf(u0.z); dst[3] = (short)f2bf(u0.w); \
        dst[4] = (short)f2bf(u1.x); dst[5] = (short)f2bf(u1.y); \
        dst[6] = (short)f2bf(u1.z); dst[7] = (short)f2bf(u1.w); }
    LOADA1(0, a0) LOADA1(1, a1) LOADA1(2, a2) LOADA1(3, a3)

    // 16 N-tiles x 4 K-steps; store with within-32 permutation
#pragma unroll
    for (int nt = 0; nt < 16; ++nt) {
        const int c = nt * 16 + l15;            // true column
        const float bv = bi[c] + bh[c];
        f32x4v acc = {bv, bv, bv, bv};
        const unsigned short* wrow = &wiL[nt * 16 + l15][lg * 8];
        bf16x8 b0 = *(const bf16x8*)(wrow + 0);
        bf16x8 b1 = *(const bf16x8*)(wrow + 32);
        bf16x8 b2 = *(const bf16x8*)(wrow + 64);
        bf16x8 b3 = *(const bf16x8*)(wrow + 96);
        MM(a0, b0, acc) MM(a1, b1, acc) MM(a2, b2, acc) MM(a3, b3, acc)

        const int pos = (c & ~31) + 2 * (c & 15) + ((c & 31) >> 4);
#pragma unroll
        for (int r = 0; r < 4; ++r)
            xproj[(size_t)(m0 + lg * 4 + r) * HH + pos] = acc[r];
    }
}

// ---------------------------------------------------------------------------
// Phase 3 (MFMA): out = hs*Wo^T + bo.  hs is bf16 in pos space; Wo staged to
// LDS bf16 PRE-PERMUTED (woL[o][pos(c)] = Wo[o][c]) so the contraction runs
// entirely in pos space (permutation-invariant dot).
// ---------------------------------------------------------------------------
#define WOPAD 264   // ushorts per woL row (528B stride: proven bank family)

__global__ __launch_bounds__(256) void gemm3_mfma(
    const unsigned short* __restrict__ hs, const float* __restrict__ Wo,
    const float* __restrict__ bo, float* __restrict__ out)
{
    __shared__ __align__(16) unsigned short woL[OO][WOPAD];   // 128 x 264 (67.6 KB)

    const int tid = threadIdx.x;
    const int wv = tid >> 6, lane = tid & 63;
    const int l15 = lane & 15, lg = lane >> 4;
    const int m0 = blockIdx.x * 64 + wv * 16;

    // stage Wo -> LDS bf16, permuted into pos space (coalesced flat reads)
    for (int e = tid; e < OO * HH; e += 256) {
        const int o = e >> 8, c = e & 255;
        const int pos = (c & ~31) + 2 * (c & 15) + ((c & 31) >> 4);
        woL[o][pos] = f2bf(Wo[e]);
    }
    __syncthreads();

    // A-frags: hs rows m0+l15 (pos-space), 8 K-subtiles, direct b128 global
    const unsigned short* hr = hs + (size_t)(m0 + l15) * HH + lg * 8;
    bf16x8 a0 = *(const bf16x8*)(hr + 0);
    bf16x8 a1 = *(const bf16x8*)(hr + 32);
    bf16x8 a2 = *(const bf16x8*)(hr + 64);
    bf16x8 a3 = *(const bf16x8*)(hr + 96);
    bf16x8 a4 = *(const bf16x8*)(hr + 128);
    bf16x8 a5 = *(const bf16x8*)(hr + 160);
    bf16x8 a6 = *(const bf16x8*)(hr + 192);
    bf16x8 a7 = *(const bf16x8*)(hr + 224);

    // 8 N-tiles x 8 K-steps
#pragma unroll
    for (int nt = 0; nt < 8; ++nt) {
        const float bv = bo[nt * 16 + l15];
        f32x4v acc = {bv, bv, bv, bv};
        const unsigned short* wrow = &woL[nt * 16 + l15][lg * 8];
        bf16x8 b0 = *(const bf16x8*)(wrow + 0);
        bf16x8 b1 = *(const bf16x8*)(wrow + 32);
        bf16x8 b2 = *(const bf16x8*)(wrow + 64);
        bf16x8 b3 = *(const bf16x8*)(wrow + 96);
        bf16x8 b4 = *(const bf16x8*)(wrow + 128);
        bf16x8 b5 = *(const bf16x8*)(wrow + 160);
        bf16x8 b6 = *(const bf16x8*)(wrow + 192);
        bf16x8 b7 = *(const bf16x8*)(wrow + 224);
        MM(a0, b0, acc) MM(a1, b1, acc) MM(a2, b2, acc) MM(a3, b3, acc)
        MM(a4, b4, acc) MM(a5, b5, acc) MM(a6, b6, acc) MM(a7, b7, acc)

#pragma unroll
        for (int r = 0; r < 4; ++r)
            out[(size_t)(m0 + lg * 4 + r) * OO + nt * 16 + l15] = acc[r];
    }
}

// ---------------------------------------------------------------------------
// Recurrence: R8 VERBATIM (best measured: 1237 us). 4 blocks x 512 threads
// (8 waves, 2/SIMD). Per wave: 32 units (2 N-tile chains of 8 MFMA), C-in = x
// (bias folded in phase 1), deferred hs stores, exp-based tanh (R12 showed
// trans ops are cheap; Pade regressed), one __syncthreads per step.
// ---------------------------------------------------------------------------
#define G 16
#define HPAD 264    // ushorts per h row (528B)

__global__ __launch_bounds__(512) __attribute__((amdgpu_waves_per_eu(2, 2)))
void rnn_recurrence_mfma(
    const float* __restrict__ xproj, const float* __restrict__ Wh,
    unsigned short* __restrict__ hs)
{
    __shared__ __align__(16) unsigned short hbl[2][G][HPAD];

    const int blk  = blockIdx.x;         // 0..3
    const int tid  = threadIdx.x;        // 0..511
    const int wave = tid >> 6;           // 0..7
    const int lane = tid & 63;
    const int l15  = lane & 15;
    const int lg   = lane >> 4;          // 0..3
    const int n0   = wave * 32;          // wave's 32-unit block

    // one-time B-frags (within-32 K-gather; slot b -> true k = kt*32+lg*4+(b>>1)+16*(b&1))
#define LOADB(nt, kt, dst) { \
        const float* wp = Wh + (size_t)(n0 + (nt)*16 + l15) * HH + (kt)*32 + lg*4; \
        dst[0] = (short)f2bf(wp[0]);  dst[1] = (short)f2bf(wp[16]); \
        dst[2] = (short)f2bf(wp[1]);  dst[3] = (short)f2bf(wp[17]); \
        dst[4] = (short)f2bf(wp[2]);  dst[5] = (short)f2bf(wp[18]); \
        dst[6] = (short)f2bf(wp[3]);  dst[7] = (short)f2bf(wp[19]); }

    bf16x8 B00, B01, B02, B03, B04, B05, B06, B07;
    bf16x8 B10, B11, B12, B13, B14, B15, B16, B17;
    LOADB(0, 0, B00) LOADB(0, 1, B01) LOADB(0, 2, B02) LOADB(0, 3, B03)
    LOADB(0, 4, B04) LOADB(0, 5, B05) LOADB(0, 6, B06) LOADB(0, 7, B07)
    LOADB(1, 0, B10) LOADB(1, 1, B11) LOADB(1, 2, B12) LOADB(1, 3, B13)
    LOADB(1, 4, B14) LOADB(1, 5, B15) LOADB(1, 6, B16) LOADB(1, 7, B17)

    // per-thread 4 batch rows (m = lg*4 + r), permuted col offset n0 + 2*l15
    const int mb = blk * G + lg * 4;
    const float* xq0 = xproj + (size_t)(mb + 0) * TT * HH + n0 + 2 * l15;
    const float* xq1 = xproj + (size_t)(mb + 1) * TT * HH + n0 + 2 * l15;
    const float* xq2 = xproj + (size_t)(mb + 2) * TT * HH + n0 + 2 * l15;
    const float* xq3 = xproj + (size_t)(mb + 3) * TT * HH + n0 + 2 * l15;
    unsigned short* hq0 = hs + (size_t)(mb + 0) * TT * HH + n0 + 2 * l15;
    unsigned short* hq1 = hs + (size_t)(mb + 1) * TT * HH + n0 + 2 * l15;
    unsigned short* hq2 = hs + (size_t)(mb + 2) * TT * HH + n0 + 2 * l15;
    unsigned short* hq3 = hs + (size_t)(mb + 3) * TT * HH + n0 + 2 * l15;

    // prologue: zero h buffer 0; load x for t=0
    for (int i = tid; i < G * HPAD / 2; i += 512)
        ((unsigned int*)hbl[0])[i] = 0u;
    float2 xv0 = *(const float2*)xq0;
    float2 xv1 = *(const float2*)xq1;
    float2 xv2 = *(const float2*)xq2;
    float2 xv3 = *(const float2*)xq3;
    __syncthreads();

    unsigned int sv0 = 0, sv1 = 0, sv2 = 0, sv3 = 0;

    for (int t = 0; t < TT; ++t) {
        const int p = t & 1;

        // A-fragments of current h (8 x ds_read_b128)
        const unsigned short* hrow = &hbl[p][l15][lg * 8];
        bf16x8 a0 = *(const bf16x8*)(hrow + 0 * 32);
        bf16x8 a1 = *(const bf16x8*)(hrow + 1 * 32);
        bf16x8 a2 = *(const bf16x8*)(hrow + 2 * 32);
        bf16x8 a3 = *(const bf16x8*)(hrow + 3 * 32);
        bf16x8 a4 = *(const bf16x8*)(hrow + 4 * 32);
        bf16x8 a5 = *(const bf16x8*)(hrow + 5 * 32);
        bf16x8 a6 = *(const bf16x8*)(hrow + 6 * 32);
        bf16x8 a7 = *(const bf16x8*)(hrow + 7 * 32);

        // deferred hs stores for t-1 (drain overlaps this whole step)
        if (t) {
            *(unsigned int*)hq0 = sv0; hq0 += HH;
            *(unsigned int*)hq1 = sv1; hq1 += HH;
            *(unsigned int*)hq2 = sv2; hq2 += HH;
            *(unsigned int*)hq3 = sv3; hq3 += HH;
        }

        // 16 MFMA: 2 chains of 8, C-in = x (bias pre-folded in phase 1)
        f32x4v c0 = {xv0.x, xv1.x, xv2.x, xv3.x};
        f32x4v c1 = {xv0.y, xv1.y, xv2.y, xv3.y};
        MM(a0, B00, c0) MM(a0, B10, c1)
        MM(a1, B01, c0) MM(a1, B11, c1)
        MM(a2, B02, c0) MM(a2, B12, c1)
        MM(a3, B03, c0) MM(a3, B13, c1)
        MM(a4, B04, c0) MM(a4, B14, c1)
        MM(a5, B05, c0) MM(a5, B15, c1)
        MM(a6, B06, c0) MM(a6, B16, c1)
        MM(a7, B07, c0) MM(a7, B17, c1)

        // epilogue: tanh both chain outputs, pack, one b32 LDS write per row
#define EPI(r, sv) { \
        float h0 = tanh_fast(c0[r]); \
        float h1 = tanh_fast(c1[r]); \
        asm("v_cvt_pk_bf16_f32 %0, %1, %2" : "=v"(sv) : "v"(h0), "v"(h1)); \
        *(unsigned int*)&hbl[p ^ 1][lg * 4 + (r)][n0 + 2 * l15] = sv; }

        EPI(0, sv0)
        EPI(1, sv1)
        EPI(2, sv2)
        EPI(3, sv3)

        // prefetch x for t+1 (pointer bump; last-step read is in-bounds junk)
        xq0 += HH; xq1 += HH; xq2 += HH; xq3 += HH;
        xv0 = *(const float2*)xq0;
        xv1 = *(const float2*)xq1;
        xv2 = *(const float2*)xq2;
        xv3 = *(const float2*)xq3;

        __syncthreads();
    }

    // final stores (t = TT-1)
    *(unsigned int*)hq0 = sv0;
    *(unsigned int*)hq1 = sv1;
    *(unsigned int*)hq2 = sv2;
    *(unsigned int*)hq3 = sv3;
}

// ---------------------------------------------------------------------------
extern "C" void kernel_launch(void* const* d_in, const int* in_sizes, int n_in,
                              void* d_out, int out_size, void* d_ws, size_t ws_size,
                              hipStream_t stream)
{
    const float* x  = (const float*)d_in[0];   // [B,T,I]
    const float* Wi = (const float*)d_in[1];   // [H,I]
    const float* bi = (const float*)d_in[2];   // [H]
    const float* Wh = (const float*)d_in[3];   // [H,H]
    const float* bh = (const float*)d_in[4];   // [H]
    const float* Wo = (const float*)d_in[5];   // [O,H]
    const float* bo = (const float*)d_in[6];   // [O]
    float* out = (float*)d_out;                // [B,T,O] fp32

    const int M = BB * TT;                     // 131072 flattened rows

    // workspace: xproj fp32 [M,H] (134MB, permuted) | hs bf16 [M,H] (67MB, permuted)
    float* xproj = (float*)d_ws;
    unsigned short* hs = (unsigned short*)((char*)d_ws + (size_t)M * HH * sizeof(float));

    // Phase 1: xproj = x*Wi^T + (bi+bh), within-32 permuted columns (MFMA)
    gemm1_mfma<<<dim3(M / 64), 256, 0, stream>>>(x, Wi, bi, bh, xproj);

    // Phase 2: recurrence (4 CUs, 8 waves each, MFMA) — R8 structure
    rnn_recurrence_mfma<<<dim3(4), 512, 0, stream>>>(xproj, Wh, hs);

    // Phase 3: out = hs*Wo^T + bo (MFMA, pos-space contraction)
    gemm3_mfma<<<dim3(M / 64), 256, 0, stream>>>(hs, Wo, bo, out);
}